// Round 14
// baseline (279.660 us; speedup 1.0000x reference)
//
#include <hip/hip_runtime.h>
#include <stdint.h>

typedef unsigned short u16;
typedef unsigned int   u32;

#define NB   2
#define NS   2048
#define NDIM 1024
#define NH   16
#define NDH  64
// SCALE * log2(e) = 0.125 * 1.4426950408889634
#define QSCALE 0.18033688011112042f

typedef __bf16 bf16x8 __attribute__((ext_vector_type(8)));
typedef float  f32x4  __attribute__((ext_vector_type(4)));

#define MFMA_BF16(a,b,c) __builtin_amdgcn_mfma_f32_16x16x32_bf16((a),(b),(c),0,0,0)

// ---------------- ws layout (bytes) ----------------
#define XBF_OFF   (256)                          // 8 MB x bf16; reused as combined attention output Ab
#define WD_OFF    (XBF_OFF  + 8*1024*1024)       // 8 MB dense quaternion weights (q,k,v,o)
#define BIAS_OFF  (WD_OFF   + 8*1024*1024)       // 16 KB fp32 biases
#define QB_OFF    (BIAS_OFF + 16384)             // 8 MB Q (bh,s,d) bf16 (roped, pre-scaled)
#define KB_OFF    (QB_OFF   + 8*1024*1024)       // 8 MB K (bh,s,d) (roped)
#define VT_OFF    (KB_OFF   + 8*1024*1024)       // 8 MB V^T (bh,d,s)
#define OP_OFF    (VT_OFF   + 8*1024*1024)       // 16 MB O partials bf16 [split][bh][s][d]
#define LP_OFF    (OP_OFF   + 16*1024*1024)      // 512 KB l partials fp32 [split][bh][s]

__device__ __forceinline__ float bf2f(u16 h){
  union { u32 u; float f; } v; v.u = ((u32)h) << 16; return v.f;
}
__device__ __forceinline__ u16 f2bf(float f){
  union { float f; u32 u; } v; v.f = f;
  u32 r = (v.u >> 16) & 1u;
  return (u16)((v.u + 0x7fffu + r) >> 16);
}
// native RNE convert — compiler emits v_cvt_pk_bf16_f32 for pairs; same rounding
// as manual f2bf (bit-identical), ~5x fewer VALU ops.
__device__ __forceinline__ u16 f2bf_rn(float f){
  union { __bf16 h; u16 u; } v; v.h = (__bf16)f; return v.u;
}
__device__ __forceinline__ float load_val(const void* p, int i, int isbf){
  return isbf ? bf2f(((const u16*)p)[i]) : ((const float*)p)[i];
}
__device__ __forceinline__ void gl_lds16(const u16* g, u16* l){
  __builtin_amdgcn_global_load_lds(
      (__attribute__((address_space(1))) void*)(uintptr_t)g,
      (__attribute__((address_space(3))) void*)(uintptr_t)l,
      16, 0, 0);
}

// ---------------- fused prep: dtype detect + x->bf16 + weight build ----------------
// Weight build read-once: one thread computes all 4 c-rows from a single
// (vr,vi,vj,vk) read. Grid 3072: blocks [0,2048) convert x, [2048,3072) build.
struct QPtrs { const void* w[16]; const void* b[4]; };

__global__ void prep_kernel(const void* __restrict__ xin, QPtrs ptrs,
                            u16* __restrict__ xbf, u16* __restrict__ wd,
                            float* __restrict__ biasf, int* __restrict__ flag){
  __shared__ int cnt;
  if (threadIdx.x == 0) cnt = 0;
  __syncthreads();
  {
    const uint4* xv = (const uint4*)xin;
    uint4 v0 = xv[threadIdx.x * 2], v1 = xv[threadIdx.x * 2 + 1];
    const u16* hh = (const u16*)&v0;
    int ok = 0;
#pragma unroll
    for (int i = 0; i < 16; ++i){
      u16 h = (i < 8) ? hh[i] : ((const u16*)&v1)[i - 8];
      int e = (h >> 7) & 0xFF;
      if ((e > 96 && e < 158) || ((h & 0x7FFF) == 0)) ok++;
    }
    atomicAdd(&cnt, ok);
  }
  __syncthreads();
  int isbf = (cnt > 3600) ? 1 : 0;
  if (blockIdx.x == 0 && threadIdx.x == 0) *flag = isbf;

  int idx = blockIdx.x * 256 + threadIdx.x;

  if (blockIdx.x < 2048){
    // ---- conv part: blocks 0..2047 cover all 8 MB of x ----
    int t = idx;
    if (isbf){
      ((uint4*)xbf)[t] = ((const uint4*)xin)[t];
    } else {
      const float4* f4 = (const float4*)xin;
      float4 a = f4[2*t], b = f4[2*t+1];
      ushort4 lo = { f2bf(a.x), f2bf(a.y), f2bf(a.z), f2bf(a.w) };
      ushort4 hi = { f2bf(b.x), f2bf(b.y), f2bf(b.z), f2bf(b.w) };
      ((ushort4*)xbf)[2*t]   = lo;
      ((ushort4*)xbf)[2*t+1] = hi;
    }
  } else {
    // ---- weight build: blocks 2048..3071, one thread per (p,m,n) ----
    int wi = idx - 2048 * 256;            // [0, 262144)
    int n = wi & 255, m = (wi >> 8) & 255, p = wi >> 16;
    int src = m * 256 + n;
    float vr = load_val(ptrs.w[p*4+0], src, isbf);
    float vi = load_val(ptrs.w[p*4+1], src, isbf);
    float vj = load_val(ptrs.w[p*4+2], src, isbf);
    float vk = load_val(ptrs.w[p*4+3], src, isbf);
    ushort4 s0 = { f2bf(vr), f2bf(-vi), f2bf(-vj), f2bf(-vk) };
    ushort4 s1 = { f2bf(vi), f2bf(vr),  f2bf(-vj), f2bf(vk)  };
    ushort4 s2 = { f2bf(vj), f2bf(vi),  f2bf(vr),  f2bf(-vk) };
    ushort4 s3 = { f2bf(vk), f2bf(-vi), f2bf(vj),  f2bf(vr)  };
    u16* base = &wd[(size_t)p * 1048576 + (size_t)(4*m) * 1024 + 4*n];
    *(ushort4*)(base)        = s0;
    *(ushort4*)(base + 1024) = s1;
    *(ushort4*)(base + 2048) = s2;
    *(ushort4*)(base + 3072) = s3;
    if (wi < 4096){
      int pp = wi >> 10, oo = wi & 1023;
      biasf[wi] = load_val(ptrs.b[pp], oo, isbf);
    }
  }
}

// ---------------- GEMM: X*Wqkv^T, fused bias+RoPE epilogue ----------------
// Proven 128^2 triple-buffer counted-vmcnt form + T1 XCD-aware block swizzle
// (bijective: 768 blocks = 8 XCDs x 96).
__global__ __launch_bounds__(256)
void gemm_qkv_kernel(const u16* __restrict__ A, const u16* __restrict__ Bw,
                     const float* __restrict__ bias,
                     u16* __restrict__ qb, u16* __restrict__ kb, u16* __restrict__ vt){
  __shared__ u16 sA[3][128 * 32];
  __shared__ u16 sB[3][128 * 32];
  int tid = threadIdx.x, w = tid >> 6, lane = tid & 63, quad = lane >> 4, l16 = lane & 15;

  // XCD swizzle: hw block i runs work ((i&7)*96 + (i>>3))
  int lid = (int)blockIdx.y * 24 + (int)blockIdx.x;
  int swz = (lid & 7) * 96 + (lid >> 3);
  int n0 = (swz % 24) * 128, m0 = (swz / 24) * 128;

  f32x4 acc[4][4];
#pragma unroll
  for (int i = 0; i < 4; ++i)
#pragma unroll
    for (int j = 0; j < 4; ++j) acc[i][j] = (f32x4){0.f, 0.f, 0.f, 0.f};

  // staging: lane -> (row rl, chunk pos cp); fetch global chunk cp ^ ((rl>>1)&3)
  int cp = lane & 3, rl = lane >> 2;
  int gc = (cp ^ ((rl >> 1) & 3)) * 8;
  const u16* ga = A  + (size_t)(m0 + w*16 + rl) * 1024 + gc;
  const u16* gb = Bw + (size_t)(n0 + w*16 + rl) * 1024 + gc;
  int ldo = w * 512 + lane * 8;
  int xorv = ((l16 >> 1) & 3) * 8;
  int mw = (w & 1) * 64, nw = (w >> 1) * 64;

  auto stage = [&](int k0, int b){
#pragma unroll
    for (int i = 0; i < 2; ++i){
      gl_lds16(ga + (size_t)i * 65536 + k0, &sA[b][ldo + i * 2048]);
      gl_lds16(gb + (size_t)i * 65536 + k0, &sB[b][ldo + i * 2048]);
    }
  };

  stage(0, 0);
  stage(32, 1);
  asm volatile("s_waitcnt vmcnt(4)" ::: "memory");   // tile 0 landed, tile 1 in flight
  __builtin_amdgcn_s_barrier();

  int bcur = 0, bnxt = 2;   // compute buffer, stage-target buffer = (it+2)%3
  for (int it = 0; it < 32; ++it){
    if (it < 30) stage((it + 2) * 32, bnxt);
    const u16* cA = sA[bcur];
    const u16* cB = sB[bcur];
    bf16x8 af[4], bfr[4];
#pragma unroll
    for (int mt = 0; mt < 4; ++mt)
      af[mt] = *(const bf16x8*)&cA[(mw + mt*16 + l16) * 32 + (quad*8 ^ xorv)];
#pragma unroll
    for (int nt = 0; nt < 4; ++nt)
      bfr[nt] = *(const bf16x8*)&cB[(nw + nt*16 + l16) * 32 + (quad*8 ^ xorv)];
#pragma unroll
    for (int mt = 0; mt < 4; ++mt)
#pragma unroll
      for (int nt = 0; nt < 4; ++nt)
        acc[mt][nt] = MFMA_BF16(af[mt], bfr[nt], acc[mt][nt]);

    // drain stage(it+1) (needed next body); keep stage(it+2) flying
    if (it < 30) asm volatile("s_waitcnt vmcnt(4)" ::: "memory");
    else         asm volatile("s_waitcnt vmcnt(0)" ::: "memory");
    __builtin_amdgcn_s_barrier();
    bcur = (bcur == 2) ? 0 : bcur + 1;
    bnxt = (bnxt == 2) ? 0 : bnxt + 1;
  }

  int proj = n0 >> 10;    // uniform per block (proj boundary is a multiple of 128)
  if (proj == 2){
    // V^T: [bh][d][s]
#pragma unroll
    for (int mt = 0; mt < 4; ++mt){
      int row = m0 + mw + mt*16 + quad*4;
      int b = row >> 11, seq0 = row & 2047;
#pragma unroll
      for (int nt = 0; nt < 4; ++nt){
        int col = n0 + nw + nt*16 + l16;
        int o = col & 1023, h = o >> 6, d = o & 63;
        float bv = bias[col];
        ushort4 pv = { f2bf_rn(acc[mt][nt][0] + bv), f2bf_rn(acc[mt][nt][1] + bv),
                       f2bf_rn(acc[mt][nt][2] + bv), f2bf_rn(acc[mt][nt][3] + bv) };
        *(ushort4*)&vt[((size_t)((b*16 + h) * 64 + d)) * 2048 + seq0] = pv;
      }
    }
  } else {
    // Q/K with fused RoPE: out = co*v + sgn*si*partner  (partner = lane xor (ax+1))
    float sc = (proj == 0) ? QSCALE : 1.0f;
    u16* dst = proj ? kb : qb;
    int c = l16 & 3;
#pragma unroll
    for (int nt = 0; nt < 4; ++nt){
      int col = n0 + nw + nt*16 + l16;
      int o = col & 1023, h = o >> 6, d = o & 63;
      int g = d >> 2;
      int ax = g % 3;
      int mask = ax + 1;
      int tbl = (ax == 0) ? 0xA : (ax == 1 ? 0x6 : 0xC);   // '+' bits by component
      float sgn = ((tbl >> c) & 1) ? 1.f : -1.f;
      float inv = __builtin_amdgcn_exp2f(-(float)g * 0.8304820237218405f); // 10000^(-g/16)
      float bv = bias[col];
#pragma unroll
      for (int mt = 0; mt < 4; ++mt){
        int row0 = m0 + mw + mt*16 + quad*4;
        int b = row0 >> 11, s0 = row0 & 2047;
        size_t obase = ((size_t)((b*16 + h) * 2048 + s0)) * 64 + d;
#pragma unroll
        for (int r = 0; r < 4; ++r){
          float v = acc[mt][nt][r] + bv;
          float vp = __shfl_xor(v, mask);
          float ang = (float)(s0 + r) * inv;
          float co = __cosf(ang) * sc;
          float si = __sinf(ang) * sc * sgn;
          dst[obase + (size_t)r * 64] = f2bf_rn(co * v + si * vp);
        }
      }
    }
  }
}

// ---------------- GEMM: attn-out * Wo^T -> d_out ----------------
// Proven round-1/2 form: triple buffer, depth-2 prefetch, counted vmcnt(3).
__global__ __launch_bounds__(256)
void gemm_o_kernel(const u16* __restrict__ A, const u16* __restrict__ Bw,
                   const float* __restrict__ bias, void* __restrict__ dout,
                   const int* __restrict__ flag){
  __shared__ u16 sA[3][64 * 32];
  __shared__ u16 sB[3][128 * 32];
  int tid = threadIdx.x, w = tid >> 6, lane = tid & 63, quad = lane >> 4, l16 = lane & 15;
  int n0 = blockIdx.x * 128, m0 = blockIdx.y * 64;

  f32x4 acc[2][4];
#pragma unroll
  for (int i = 0; i < 2; ++i)
#pragma unroll
    for (int j = 0; j < 4; ++j) acc[i][j] = (f32x4){0.f, 0.f, 0.f, 0.f};

  int cp = lane & 3, rl = lane >> 2;
  int gc = (cp ^ ((rl >> 1) & 3)) * 8;
  int xorv = ((l16 >> 1) & 3) * 8;
  int mw = (w & 1) * 32, nw = (w >> 1) * 64;

  auto stage = [&](int k0, int b){
#pragma unroll
    for (int i = 0; i < 3; ++i){
      int ch = w * 3 + i;                 // 12 chunks: 4 sA + 8 sB
      int lr = (ch < 4 ? ch : ch - 4) * 16 + rl;
      int eo = (ch < 4 ? ch : ch - 4) * 512 + lane * 8;
      if (ch < 4) gl_lds16(A  + (size_t)(m0 + lr) * 1024 + k0 + gc, &sA[b][eo]);
      else        gl_lds16(Bw + (size_t)(n0 + lr) * 1024 + k0 + gc, &sB[b][eo]);
    }
  };

  stage(0, 0);
  stage(32, 1);
  asm volatile("s_waitcnt vmcnt(3)" ::: "memory");   // tile 0 landed, tile 1 in flight
  __builtin_amdgcn_s_barrier();

  int bcur = 0, bnxt = 2;
  for (int it = 0; it < 32; ++it){
    if (it < 30) stage((it + 2) * 32, bnxt);
    const u16* cA = sA[bcur];
    const u16* cB = sB[bcur];
    bf16x8 af[2], bfr[4];
#pragma unroll
    for (int mt = 0; mt < 2; ++mt)
      af[mt] = *(const bf16x8*)&cA[(mw + mt*16 + l16) * 32 + (quad*8 ^ xorv)];
#pragma unroll
    for (int nt = 0; nt < 4; ++nt)
      bfr[nt] = *(const bf16x8*)&cB[(nw + nt*16 + l16) * 32 + (quad*8 ^ xorv)];
#pragma unroll
    for (int mt = 0; mt < 2; ++mt)
#pragma unroll
      for (int nt = 0; nt < 4; ++nt)
        acc[mt][nt] = MFMA_BF16(af[mt], bfr[nt], acc[mt][nt]);

    if (it < 30) asm volatile("s_waitcnt vmcnt(3)" ::: "memory");
    else         asm volatile("s_waitcnt vmcnt(0)" ::: "memory");
    __builtin_amdgcn_s_barrier();
    bcur = (bcur == 2) ? 0 : bcur + 1;
    bnxt = (bnxt == 2) ? 0 : bnxt + 1;
  }

  int isbf = *flag;
#pragma unroll
  for (int mt = 0; mt < 2; ++mt){
    int row = m0 + mw + mt*16 + quad*4;
#pragma unroll
    for (int nt = 0; nt < 4; ++nt){
      int col = n0 + nw + nt*16 + l16;
      float bv = bias[col];
#pragma unroll
      for (int r = 0; r < 4; ++r){
        float val = acc[mt][nt][r] + bv;
        size_t addr = (size_t)(row + r) * 1024 + col;
        if (isbf) ((u16*)dout)[addr] = f2bf(val);
        else      ((float*)dout)[addr] = val;
      }
    }
  }
}

// ---------------- flash attention v12: 32-row slabs, 2048 blocks (~14 waves/CU) ----------------
// Round-14: first TRUE waves/CU increase of the session. All prior occupancy
// experiments kept 8 waves/CU (grid-capped at 4 blocks/CU); this halves the
// q-slab to 32 rows (g=1 per warp: each warp owns 16 rows) and doubles the grid
// to (32,2,32) = 2048 blocks -> ~7 resident blocks/CU (LDS 21 KB) = ~14 waves.
// Cost: per-row K-stage/bk-read overhead doubles (inverse of R12's failed
// trade). 64 slabs, pair-balanced (63-z, z): total tiles/pair = 33 uniform;
// split-2 contiguous. OP/LP layout and combine unchanged.
#define SPT 20

__global__ __launch_bounds__(128, 2)
void attn_kernel(const u16* __restrict__ Q, const u16* __restrict__ K,
                 const u16* __restrict__ Vt, u16* __restrict__ OP,
                 float* __restrict__ LP){
  __shared__ u16 sK[2][4096];           // 64 x 64 K-tile, double buffered (16 KB)
  __shared__ u16 sPT[2][64 * SPT];      // [warp] P-transpose scratch (5 KB)
  int lid = (int)blockIdx.x + 32 * (int)blockIdx.y + 64 * (int)blockIdx.z;
  int bh  = (lid & 7) * 4 + ((lid >> 3) & 3);   // XCD-clustered (4 heads/XCD L2)
  int spl = (lid >> 5) & 1;
  int z   = lid >> 6;                   // 0..31
  int tid = threadIdx.x, w = tid >> 6, lane = tid & 63, quad = lane >> 4, l16 = lane & 15;
  size_t kbase = (size_t)bh * 2048 * 64;
  size_t vbase = (size_t)bh * 64 * 2048;
  u16* spw = &sPT[w][0];

  auto stage = [&](int kt, int b){
    int kcol = kt * 64;
#pragma unroll
    for (int p = 0; p < 4; ++p){
      int sb = (w*4 + p) * 64;          // wave-uniform LDS base (gl_lds requirement)
      int slot = sb + lane;
      int row = slot >> 3, dc = (slot & 7) ^ (row & 7);
      gl_lds16(K + kbase + (size_t)(kcol + row) * 64 + dc*8, &sK[b][sb * 8]);
    }
  };

  for (int item = 0; item < 2; ++item){
    int s2 = item ? z : 63 - z;         // 32-row slab index, rows [s2*32, s2*32+31]
    int rowbase = s2 * 32 + w * 16;     // warp's 16 q-rows

    bf16x8 qf[2];
#pragma unroll
    for (int kc = 0; kc < 2; ++kc)
      qf[kc] = *(const bf16x8*)(Q + kbase + (size_t)(rowbase + l16) * 64 + kc*32 + quad*8);

    f32x4 oaccT[4];
    float lsum[4];
#pragma unroll
    for (int i = 0; i < 4; ++i){ oaccT[i] = (f32x4){0.f,0.f,0.f,0.f}; lsum[i] = 0.f; }

    int ntot = (s2 >> 1) + 1;           // K-tiles covering rows [0, s2*32+31]
    int c = (ntot + 1) >> 1;
    int kt0 = spl ? c : 0;
    int ntiles = spl ? (ntot - c) : c;

    if (ntiles > 0) stage(kt0, 0);
    for (int i = 0; i < ntiles; ++i){
      int kcol = (kt0 + i) * 64;
      __syncthreads();
      if (i + 1 < ntiles) stage(kt0 + i + 1, (i + 1) & 1);
      const u16* bK = sK[i & 1];

      if (kcol <= rowbase + 15){
        bf16x8 vf[4][2];
#pragma unroll
        for (int dn = 0; dn < 4; ++dn)
#pragma unroll
          for (int kc = 0; kc < 2; ++kc)
            vf[dn][kc] = *(const bf16x8*)(Vt + vbase + (size_t)(dn*16 + l16) * 2048
                                          + kcol + kc*32 + quad*8);
        bf16x8 bk[2][4];
#pragma unroll
        for (int kc = 0; kc < 2; ++kc)
#pragma unroll
          for (int nt = 0; nt < 4; ++nt){
            int rw = nt*16 + l16;
            int ch = ((kc*4 + quad) ^ (rw & 7)) * 8;
            bk[kc][nt] = *(const bf16x8*)&bK[rw*64 + ch];
          }
        int G0 = rowbase;
        f32x4 sacc[4];
#pragma unroll
        for (int nt = 0; nt < 4; ++nt) sacc[nt] = (f32x4){0.f,0.f,0.f,0.f};
#pragma unroll
        for (int kc = 0; kc < 2; ++kc)
#pragma unroll
          for (int nt = 0; nt < 4; ++nt)
            sacc[nt] = MFMA_BF16(qf[kc], bk[kc][nt], sacc[nt]);

        if (kcol + 63 > G0){
#pragma unroll
          for (int nt = 0; nt < 4; ++nt){
            int col = kcol + nt*16 + l16;
            ushort4 pv;
#pragma unroll
            for (int r = 0; r < 4; ++r){
              int row = G0 + quad*4 + r;
              float pp = (col <= row) ? __builtin_amdgcn_exp2f(sacc[nt][r]) : 0.f;
              lsum[r] += pp;
              ((u16*)&pv)[r] = f2bf_rn(pp);
            }
            *(ushort4*)&spw[(nt*16 + l16) * SPT + quad*4] = pv;
          }
        } else {
#pragma unroll
          for (int nt = 0; nt < 4; ++nt){
            ushort4 pv;
#pragma unroll
            for (int r = 0; r < 4; ++r){
              float pp = __builtin_amdgcn_exp2f(sacc[nt][r]);
              lsum[r] += pp;
              ((u16*)&pv)[r] = f2bf_rn(pp);
            }
            *(ushort4*)&spw[(nt*16 + l16) * SPT + quad*4] = pv;
          }
        }
#pragma unroll
        for (int kc = 0; kc < 2; ++kc){
          bf16x8 pf;
#pragma unroll
          for (int j = 0; j < 8; ++j)
            pf[j] = ((const __bf16*)spw)[(kc*32 + quad*8 + j) * SPT + l16];
#pragma unroll
          for (int dn = 0; dn < 4; ++dn)
            oaccT[dn] = MFMA_BF16(vf[dn][kc], pf, oaccT[dn]);
        }
      }
    }

    float* scr = (float*)spw;
#pragma unroll
    for (int r = 0; r < 4; ++r){
      float l = lsum[r];
      l += __shfl_xor(l, 1); l += __shfl_xor(l, 2);
      l += __shfl_xor(l, 4); l += __shfl_xor(l, 8);
      if (l16 == 0) scr[quad*4 + r] = l;
    }
    float lrow = scr[l16];

    size_t obase = ((size_t)(spl*32 + bh)) * 2048;
    {
      int row = rowbase + l16;
      if (quad == 0) LP[obase + row] = lrow;
#pragma unroll
      for (int dn = 0; dn < 4; ++dn){
        ushort4 ov = { f2bf_rn(oaccT[dn][0]), f2bf_rn(oaccT[dn][1]),
                       f2bf_rn(oaccT[dn][2]), f2bf_rn(oaccT[dn][3]) };
        *(ushort4*)&OP[(obase + row) * 64 + dn*16 + quad*4] = ov;
      }
    }

    // protect sK / sPT reuse before the second item's staging begins
    __syncthreads();
  }
}

// ---------------- combine splits -> Ab (b, s, h*64+d) bf16 ----------------
__global__ void combine_kernel(const u16* __restrict__ OP, const float* __restrict__ LP,
                               u16* __restrict__ Ab){
  int idx = blockIdx.x * 256 + threadIdx.x;
  int dc = idx & 7, s = (idx >> 3) & 2047, bh = idx >> 14;
  size_t r0 = (size_t)bh * 2048 + s, r1 = (size_t)(32 + bh) * 2048 + s;
  float invl = 1.f / (LP[r0] + LP[r1]);
  union { uint4 v; u16 h[8]; } a0, a1, o;
  a0.v = *(const uint4*)&OP[r0 * 64 + dc*8];
  a1.v = *(const uint4*)&OP[r1 * 64 + dc*8];
#pragma unroll
  for (int j = 0; j < 8; ++j)
    o.h[j] = f2bf((bf2f(a0.h[j]) + bf2f(a1.h[j])) * invl);
  int b = bh >> 4, h = bh & 15;
  *(uint4*)&Ab[((size_t)(b*2048 + s)) * 1024 + h*64 + dc*8] = o.v;
}

// ---------------- launcher ----------------
extern "C" void kernel_launch(void* const* d_in, const int* in_sizes, int n_in,
                              void* d_out, int out_size, void* d_ws, size_t ws_size,
                              hipStream_t stream){
  (void)in_sizes; (void)n_in; (void)out_size; (void)ws_size;
  char* ws = (char*)d_ws;
  int*   flag  = (int*)ws;
  u16*   Xbf   = (u16*)(ws + XBF_OFF);
  u16*   Wd    = (u16*)(ws + WD_OFF);
  float* biasf = (float*)(ws + BIAS_OFF);
  u16*   Qb    = (u16*)(ws + QB_OFF);
  u16*   Kb    = (u16*)(ws + KB_OFF);
  u16*   Vt    = (u16*)(ws + VT_OFF);
  u16*   OP    = (u16*)(ws + OP_OFF);
  float* LP    = (float*)(ws + LP_OFF);
  u16*   Ab    = Xbf;   // x no longer needed after gemm_qkv; reuse as attn output

  QPtrs ptrs;
  for (int p = 0; p < 4; ++p){
    for (int wi = 0; wi < 4; ++wi) ptrs.w[p*4 + wi] = d_in[2 + p*5 + wi];
    ptrs.b[p] = d_in[2 + p*5 + 4];
  }

  prep_kernel<<<3072, 256, 0, stream>>>(d_in[0], ptrs, Xbf, Wd, biasf, flag);
  gemm_qkv_kernel<<<dim3(24, 32), 256, 0, stream>>>(Xbf, Wd, biasf, Qb, Kb, Vt);
  attn_kernel<<<dim3(32, 2, 32), 128, 0, stream>>>(Qb, Kb, Vt, OP, LP);
  combine_kernel<<<2048, 256, 0, stream>>>(OP, LP, Ab);
  gemm_o_kernel<<<dim3(8, 64), 256, 0, stream>>>(Ab, Wd + 3*1048576, biasf + 3072,
                                                 d_out, flag);
}

// Round 15
// 240.033 us; speedup vs baseline: 1.1651x; 1.1651x over previous
//
#include <hip/hip_runtime.h>
#include <stdint.h>

typedef unsigned short u16;
typedef unsigned int   u32;

#define NB   2
#define NS   2048
#define NDIM 1024
#define NH   16
#define NDH  64
// SCALE * log2(e) = 0.125 * 1.4426950408889634
#define QSCALE 0.18033688011112042f

typedef __bf16 bf16x8 __attribute__((ext_vector_type(8)));
typedef float  f32x4  __attribute__((ext_vector_type(4)));

#define MFMA_BF16(a,b,c) __builtin_amdgcn_mfma_f32_16x16x32_bf16((a),(b),(c),0,0,0)

// ---------------- ws layout (bytes) ----------------
#define XBF_OFF   (256)                          // 8 MB x bf16; reused as combined attention output Ab
#define WD_OFF    (XBF_OFF  + 8*1024*1024)       // 8 MB dense quaternion weights (q,k,v,o)
#define BIAS_OFF  (WD_OFF   + 8*1024*1024)       // 16 KB fp32 biases
#define QB_OFF    (BIAS_OFF + 16384)             // 8 MB Q (bh,s,d) bf16 (roped, pre-scaled)
#define KB_OFF    (QB_OFF   + 8*1024*1024)       // 8 MB K (bh,s,d) (roped)
#define VT_OFF    (KB_OFF   + 8*1024*1024)       // 8 MB V^T (bh,d,s)
#define OP_OFF    (VT_OFF   + 8*1024*1024)       // 16 MB O partials bf16 [split][bh][s][d]
#define LP_OFF    (OP_OFF   + 16*1024*1024)      // 512 KB l partials fp32 [split][bh][s]

__device__ __forceinline__ float bf2f(u16 h){
  union { u32 u; float f; } v; v.u = ((u32)h) << 16; return v.f;
}
__device__ __forceinline__ u16 f2bf(float f){
  union { float f; u32 u; } v; v.f = f;
  u32 r = (v.u >> 16) & 1u;
  return (u16)((v.u + 0x7fffu + r) >> 16);
}
// native RNE convert — compiler emits v_cvt_pk_bf16_f32 for pairs; same rounding
// as manual f2bf (bit-identical), ~5x fewer VALU ops.
__device__ __forceinline__ u16 f2bf_rn(float f){
  union { __bf16 h; u16 u; } v; v.h = (__bf16)f; return v.u;
}
__device__ __forceinline__ float load_val(const void* p, int i, int isbf){
  return isbf ? bf2f(((const u16*)p)[i]) : ((const float*)p)[i];
}
__device__ __forceinline__ void gl_lds16(const u16* g, u16* l){
  __builtin_amdgcn_global_load_lds(
      (__attribute__((address_space(1))) void*)(uintptr_t)g,
      (__attribute__((address_space(3))) void*)(uintptr_t)l,
      16, 0, 0);
}

// ---------------- fused prep: dtype detect + x->bf16 + weight build ----------------
// Weight build read-once: one thread computes all 4 c-rows from a single
// (vr,vi,vj,vk) read. Grid 3072: blocks [0,2048) convert x, [2048,3072) build.
struct QPtrs { const void* w[16]; const void* b[4]; };

__global__ void prep_kernel(const void* __restrict__ xin, QPtrs ptrs,
                            u16* __restrict__ xbf, u16* __restrict__ wd,
                            float* __restrict__ biasf, int* __restrict__ flag){
  __shared__ int cnt;
  if (threadIdx.x == 0) cnt = 0;
  __syncthreads();
  {
    const uint4* xv = (const uint4*)xin;
    uint4 v0 = xv[threadIdx.x * 2], v1 = xv[threadIdx.x * 2 + 1];
    const u16* hh = (const u16*)&v0;
    int ok = 0;
#pragma unroll
    for (int i = 0; i < 16; ++i){
      u16 h = (i < 8) ? hh[i] : ((const u16*)&v1)[i - 8];
      int e = (h >> 7) & 0xFF;
      if ((e > 96 && e < 158) || ((h & 0x7FFF) == 0)) ok++;
    }
    atomicAdd(&cnt, ok);
  }
  __syncthreads();
  int isbf = (cnt > 3600) ? 1 : 0;
  if (blockIdx.x == 0 && threadIdx.x == 0) *flag = isbf;

  int idx = blockIdx.x * 256 + threadIdx.x;

  if (blockIdx.x < 2048){
    // ---- conv part: blocks 0..2047 cover all 8 MB of x ----
    int t = idx;
    if (isbf){
      ((uint4*)xbf)[t] = ((const uint4*)xin)[t];
    } else {
      const float4* f4 = (const float4*)xin;
      float4 a = f4[2*t], b = f4[2*t+1];
      ushort4 lo = { f2bf(a.x), f2bf(a.y), f2bf(a.z), f2bf(a.w) };
      ushort4 hi = { f2bf(b.x), f2bf(b.y), f2bf(b.z), f2bf(b.w) };
      ((ushort4*)xbf)[2*t]   = lo;
      ((ushort4*)xbf)[2*t+1] = hi;
    }
  } else {
    // ---- weight build: blocks 2048..3071, one thread per (p,m,n) ----
    int wi = idx - 2048 * 256;            // [0, 262144)
    int n = wi & 255, m = (wi >> 8) & 255, p = wi >> 16;
    int src = m * 256 + n;
    float vr = load_val(ptrs.w[p*4+0], src, isbf);
    float vi = load_val(ptrs.w[p*4+1], src, isbf);
    float vj = load_val(ptrs.w[p*4+2], src, isbf);
    float vk = load_val(ptrs.w[p*4+3], src, isbf);
    ushort4 s0 = { f2bf(vr), f2bf(-vi), f2bf(-vj), f2bf(-vk) };
    ushort4 s1 = { f2bf(vi), f2bf(vr),  f2bf(-vj), f2bf(vk)  };
    ushort4 s2 = { f2bf(vj), f2bf(vi),  f2bf(vr),  f2bf(-vk) };
    ushort4 s3 = { f2bf(vk), f2bf(-vi), f2bf(vj),  f2bf(vr)  };
    u16* base = &wd[(size_t)p * 1048576 + (size_t)(4*m) * 1024 + 4*n];
    *(ushort4*)(base)        = s0;
    *(ushort4*)(base + 1024) = s1;
    *(ushort4*)(base + 2048) = s2;
    *(ushort4*)(base + 3072) = s3;
    if (wi < 4096){
      int pp = wi >> 10, oo = wi & 1023;
      biasf[wi] = load_val(ptrs.b[pp], oo, isbf);
    }
  }
}

// ---------------- GEMM: X*Wqkv^T, fused bias+RoPE epilogue ----------------
// Proven 128^2 triple-buffer counted-vmcnt form + T1 XCD-aware block swizzle
// (bijective: 768 blocks = 8 XCDs x 96).
__global__ __launch_bounds__(256)
void gemm_qkv_kernel(const u16* __restrict__ A, const u16* __restrict__ Bw,
                     const float* __restrict__ bias,
                     u16* __restrict__ qb, u16* __restrict__ kb, u16* __restrict__ vt){
  __shared__ u16 sA[3][128 * 32];
  __shared__ u16 sB[3][128 * 32];
  int tid = threadIdx.x, w = tid >> 6, lane = tid & 63, quad = lane >> 4, l16 = lane & 15;

  // XCD swizzle: hw block i runs work ((i&7)*96 + (i>>3))
  int lid = (int)blockIdx.y * 24 + (int)blockIdx.x;
  int swz = (lid & 7) * 96 + (lid >> 3);
  int n0 = (swz % 24) * 128, m0 = (swz / 24) * 128;

  f32x4 acc[4][4];
#pragma unroll
  for (int i = 0; i < 4; ++i)
#pragma unroll
    for (int j = 0; j < 4; ++j) acc[i][j] = (f32x4){0.f, 0.f, 0.f, 0.f};

  // staging: lane -> (row rl, chunk pos cp); fetch global chunk cp ^ ((rl>>1)&3)
  int cp = lane & 3, rl = lane >> 2;
  int gc = (cp ^ ((rl >> 1) & 3)) * 8;
  const u16* ga = A  + (size_t)(m0 + w*16 + rl) * 1024 + gc;
  const u16* gb = Bw + (size_t)(n0 + w*16 + rl) * 1024 + gc;
  int ldo = w * 512 + lane * 8;
  int xorv = ((l16 >> 1) & 3) * 8;
  int mw = (w & 1) * 64, nw = (w >> 1) * 64;

  auto stage = [&](int k0, int b){
#pragma unroll
    for (int i = 0; i < 2; ++i){
      gl_lds16(ga + (size_t)i * 65536 + k0, &sA[b][ldo + i * 2048]);
      gl_lds16(gb + (size_t)i * 65536 + k0, &sB[b][ldo + i * 2048]);
    }
  };

  stage(0, 0);
  stage(32, 1);
  asm volatile("s_waitcnt vmcnt(4)" ::: "memory");   // tile 0 landed, tile 1 in flight
  __builtin_amdgcn_s_barrier();

  int bcur = 0, bnxt = 2;   // compute buffer, stage-target buffer = (it+2)%3
  for (int it = 0; it < 32; ++it){
    if (it < 30) stage((it + 2) * 32, bnxt);
    const u16* cA = sA[bcur];
    const u16* cB = sB[bcur];
    bf16x8 af[4], bfr[4];
#pragma unroll
    for (int mt = 0; mt < 4; ++mt)
      af[mt] = *(const bf16x8*)&cA[(mw + mt*16 + l16) * 32 + (quad*8 ^ xorv)];
#pragma unroll
    for (int nt = 0; nt < 4; ++nt)
      bfr[nt] = *(const bf16x8*)&cB[(nw + nt*16 + l16) * 32 + (quad*8 ^ xorv)];
#pragma unroll
    for (int mt = 0; mt < 4; ++mt)
#pragma unroll
      for (int nt = 0; nt < 4; ++nt)
        acc[mt][nt] = MFMA_BF16(af[mt], bfr[nt], acc[mt][nt]);

    // drain stage(it+1) (needed next body); keep stage(it+2) flying
    if (it < 30) asm volatile("s_waitcnt vmcnt(4)" ::: "memory");
    else         asm volatile("s_waitcnt vmcnt(0)" ::: "memory");
    __builtin_amdgcn_s_barrier();
    bcur = (bcur == 2) ? 0 : bcur + 1;
    bnxt = (bnxt == 2) ? 0 : bnxt + 1;
  }

  int proj = n0 >> 10;    // uniform per block (proj boundary is a multiple of 128)
  if (proj == 2){
    // V^T: [bh][d][s]
#pragma unroll
    for (int mt = 0; mt < 4; ++mt){
      int row = m0 + mw + mt*16 + quad*4;
      int b = row >> 11, seq0 = row & 2047;
#pragma unroll
      for (int nt = 0; nt < 4; ++nt){
        int col = n0 + nw + nt*16 + l16;
        int o = col & 1023, h = o >> 6, d = o & 63;
        float bv = bias[col];
        ushort4 pv = { f2bf_rn(acc[mt][nt][0] + bv), f2bf_rn(acc[mt][nt][1] + bv),
                       f2bf_rn(acc[mt][nt][2] + bv), f2bf_rn(acc[mt][nt][3] + bv) };
        *(ushort4*)&vt[((size_t)((b*16 + h) * 64 + d)) * 2048 + seq0] = pv;
      }
    }
  } else {
    // Q/K with fused RoPE: out = co*v + sgn*si*partner  (partner = lane xor (ax+1))
    float sc = (proj == 0) ? QSCALE : 1.0f;
    u16* dst = proj ? kb : qb;
    int c = l16 & 3;
#pragma unroll
    for (int nt = 0; nt < 4; ++nt){
      int col = n0 + nw + nt*16 + l16;
      int o = col & 1023, h = o >> 6, d = o & 63;
      int g = d >> 2;
      int ax = g % 3;
      int mask = ax + 1;
      int tbl = (ax == 0) ? 0xA : (ax == 1 ? 0x6 : 0xC);   // '+' bits by component
      float sgn = ((tbl >> c) & 1) ? 1.f : -1.f;
      float inv = __builtin_amdgcn_exp2f(-(float)g * 0.8304820237218405f); // 10000^(-g/16)
      float bv = bias[col];
#pragma unroll
      for (int mt = 0; mt < 4; ++mt){
        int row0 = m0 + mw + mt*16 + quad*4;
        int b = row0 >> 11, s0 = row0 & 2047;
        size_t obase = ((size_t)((b*16 + h) * 2048 + s0)) * 64 + d;
#pragma unroll
        for (int r = 0; r < 4; ++r){
          float v = acc[mt][nt][r] + bv;
          float vp = __shfl_xor(v, mask);
          float ang = (float)(s0 + r) * inv;
          float co = __cosf(ang) * sc;
          float si = __sinf(ang) * sc * sgn;
          dst[obase + (size_t)r * 64] = f2bf_rn(co * v + si * vp);
        }
      }
    }
  }
}

// ---------------- GEMM: attn-out * Wo^T -> d_out ----------------
// Proven round-1/2 form: triple buffer, depth-2 prefetch, counted vmcnt(3).
__global__ __launch_bounds__(256)
void gemm_o_kernel(const u16* __restrict__ A, const u16* __restrict__ Bw,
                   const float* __restrict__ bias, void* __restrict__ dout,
                   const int* __restrict__ flag){
  __shared__ u16 sA[3][64 * 32];
  __shared__ u16 sB[3][128 * 32];
  int tid = threadIdx.x, w = tid >> 6, lane = tid & 63, quad = lane >> 4, l16 = lane & 15;
  int n0 = blockIdx.x * 128, m0 = blockIdx.y * 64;

  f32x4 acc[2][4];
#pragma unroll
  for (int i = 0; i < 2; ++i)
#pragma unroll
    for (int j = 0; j < 4; ++j) acc[i][j] = (f32x4){0.f, 0.f, 0.f, 0.f};

  int cp = lane & 3, rl = lane >> 2;
  int gc = (cp ^ ((rl >> 1) & 3)) * 8;
  int xorv = ((l16 >> 1) & 3) * 8;
  int mw = (w & 1) * 32, nw = (w >> 1) * 64;

  auto stage = [&](int k0, int b){
#pragma unroll
    for (int i = 0; i < 3; ++i){
      int ch = w * 3 + i;                 // 12 chunks: 4 sA + 8 sB
      int lr = (ch < 4 ? ch : ch - 4) * 16 + rl;
      int eo = (ch < 4 ? ch : ch - 4) * 512 + lane * 8;
      if (ch < 4) gl_lds16(A  + (size_t)(m0 + lr) * 1024 + k0 + gc, &sA[b][eo]);
      else        gl_lds16(Bw + (size_t)(n0 + lr) * 1024 + k0 + gc, &sB[b][eo]);
    }
  };

  stage(0, 0);
  stage(32, 1);
  asm volatile("s_waitcnt vmcnt(3)" ::: "memory");   // tile 0 landed, tile 1 in flight
  __builtin_amdgcn_s_barrier();

  int bcur = 0, bnxt = 2;
  for (int it = 0; it < 32; ++it){
    if (it < 30) stage((it + 2) * 32, bnxt);
    const u16* cA = sA[bcur];
    const u16* cB = sB[bcur];
    bf16x8 af[2], bfr[4];
#pragma unroll
    for (int mt = 0; mt < 2; ++mt)
      af[mt] = *(const bf16x8*)&cA[(mw + mt*16 + l16) * 32 + (quad*8 ^ xorv)];
#pragma unroll
    for (int nt = 0; nt < 4; ++nt)
      bfr[nt] = *(const bf16x8*)&cB[(nw + nt*16 + l16) * 32 + (quad*8 ^ xorv)];
#pragma unroll
    for (int mt = 0; mt < 2; ++mt)
#pragma unroll
      for (int nt = 0; nt < 4; ++nt)
        acc[mt][nt] = MFMA_BF16(af[mt], bfr[nt], acc[mt][nt]);

    if (it < 30) asm volatile("s_waitcnt vmcnt(3)" ::: "memory");
    else         asm volatile("s_waitcnt vmcnt(0)" ::: "memory");
    __builtin_amdgcn_s_barrier();
    bcur = (bcur == 2) ? 0 : bcur + 1;
    bnxt = (bnxt == 2) ? 0 : bnxt + 1;
  }

  int isbf = *flag;
#pragma unroll
  for (int mt = 0; mt < 2; ++mt){
    int row = m0 + mw + mt*16 + quad*4;
#pragma unroll
    for (int nt = 0; nt < 4; ++nt){
      int col = n0 + nw + nt*16 + l16;
      float bv = bias[col];
#pragma unroll
      for (int r = 0; r < 4; ++r){
        float val = acc[mt][nt][r] + bv;
        size_t addr = (size_t)(row + r) * 1024 + col;
        if (isbf) ((u16*)dout)[addr] = f2bf(val);
        else      ((float*)dout)[addr] = val;
      }
    }
  }
}

// ---------------- flash attention v8 (converged optimum: 47.8-49.1 us) ----------------
// 2-warp blocks (4/CU), 64-row slabs, pair-balanced splits, XCD-clustered
// bijective lid decode, per-g P-scratch. The work-per-block axis is falsified
// in BOTH directions: 128-row slabs (R12) lost to TLP collapse, 32-row slabs
// (R14) lost 2x to doubled per-tile fixed cost. This form is the optimum.
#define SPT 20

__global__ __launch_bounds__(128, 2)
void attn_kernel(const u16* __restrict__ Q, const u16* __restrict__ K,
                 const u16* __restrict__ Vt, u16* __restrict__ OP,
                 float* __restrict__ LP){
  __shared__ u16 sK[2][4096];           // 64 x 64 K-tile, double buffered (16 KB)
  __shared__ u16 sPT[2][2][64 * SPT];   // [warp][g] P-transpose scratch (10 KB)
  int lid = (int)blockIdx.x + 32 * (int)blockIdx.y + 64 * (int)blockIdx.z;
  int bh  = (lid & 7) * 4 + ((lid >> 3) & 3);
  int spl = (lid >> 5) & 1;
  int z   = lid >> 6;
  int tid = threadIdx.x, w = tid >> 6, lane = tid & 63, quad = lane >> 4, l16 = lane & 15;
  size_t kbase = (size_t)bh * 2048 * 64;
  size_t vbase = (size_t)bh * 64 * 2048;

  auto stage = [&](int kt, int b){
    int kcol = kt * 64;
#pragma unroll
    for (int p = 0; p < 4; ++p){
      int sb = (w*4 + p) * 64;          // wave-uniform LDS base (gl_lds requirement)
      int slot = sb + lane;
      int row = slot >> 3, dc = (slot & 7) ^ (row & 7);
      gl_lds16(K + kbase + (size_t)(kcol + row) * 64 + dc*8, &sK[b][sb * 8]);
    }
  };

  for (int item = 0; item < 2; ++item){
    int s2 = item ? z : 31 - z;         // q-slab index, rows [s2*64, s2*64+63]
    int rowbase = s2 * 64 + w * 32;

    bf16x8 qf[2][2];
#pragma unroll
    for (int g = 0; g < 2; ++g)
#pragma unroll
      for (int kc = 0; kc < 2; ++kc)
        qf[g][kc] = *(const bf16x8*)(Q + kbase + (size_t)(rowbase + g*16 + l16) * 64 + kc*32 + quad*8);

    f32x4 oaccT[2][4];
    float lsum[2][4];
#pragma unroll
    for (int g = 0; g < 2; ++g)
#pragma unroll
      for (int i = 0; i < 4; ++i){ oaccT[g][i] = (f32x4){0.f,0.f,0.f,0.f}; lsum[g][i] = 0.f; }

    int c = (s2 + 2) >> 1;              // ceil((s2+1)/2)
    int kt0 = spl ? c : 0;
    int ntiles = spl ? (s2 + 1 - c) : c;

    stage(kt0, 0);
    for (int i = 0; i < ntiles; ++i){
      int kcol = (kt0 + i) * 64;
      __syncthreads();
      if (i + 1 < ntiles) stage(kt0 + i + 1, (i + 1) & 1);
      const u16* bK = sK[i & 1];

      if (kcol <= rowbase + 31){
        bf16x8 vf[4][2];
#pragma unroll
        for (int dn = 0; dn < 4; ++dn)
#pragma unroll
          for (int kc = 0; kc < 2; ++kc)
            vf[dn][kc] = *(const bf16x8*)(Vt + vbase + (size_t)(dn*16 + l16) * 2048
                                          + kcol + kc*32 + quad*8);
        bf16x8 bk[2][4];
#pragma unroll
        for (int kc = 0; kc < 2; ++kc)
#pragma unroll
          for (int nt = 0; nt < 4; ++nt){
            int rw = nt*16 + l16;
            int ch = ((kc*4 + quad) ^ (rw & 7)) * 8;
            bk[kc][nt] = *(const bf16x8*)&bK[rw*64 + ch];
          }
#pragma unroll
        for (int g = 0; g < 2; ++g){
          int G0 = rowbase + g*16;
          if (kcol <= G0 + 15){
            u16* spg = &sPT[w][g][0];
            f32x4 sacc[4];
#pragma unroll
            for (int nt = 0; nt < 4; ++nt) sacc[nt] = (f32x4){0.f,0.f,0.f,0.f};
#pragma unroll
            for (int kc = 0; kc < 2; ++kc)
#pragma unroll
              for (int nt = 0; nt < 4; ++nt)
                sacc[nt] = MFMA_BF16(qf[g][kc], bk[kc][nt], sacc[nt]);

            if (kcol + 63 > G0){
#pragma unroll
              for (int nt = 0; nt < 4; ++nt){
                int col = kcol + nt*16 + l16;
                ushort4 pv;
#pragma unroll
                for (int r = 0; r < 4; ++r){
                  int row = G0 + quad*4 + r;
                  float pp = (col <= row) ? __builtin_amdgcn_exp2f(sacc[nt][r]) : 0.f;
                  lsum[g][r] += pp;
                  ((u16*)&pv)[r] = f2bf_rn(pp);
                }
                *(ushort4*)&spg[(nt*16 + l16) * SPT + quad*4] = pv;
              }
            } else {
#pragma unroll
              for (int nt = 0; nt < 4; ++nt){
                ushort4 pv;
#pragma unroll
                for (int r = 0; r < 4; ++r){
                  float pp = __builtin_amdgcn_exp2f(sacc[nt][r]);
                  lsum[g][r] += pp;
                  ((u16*)&pv)[r] = f2bf_rn(pp);
                }
                *(ushort4*)&spg[(nt*16 + l16) * SPT + quad*4] = pv;
              }
            }
#pragma unroll
            for (int kc = 0; kc < 2; ++kc){
              bf16x8 pf;
#pragma unroll
              for (int j = 0; j < 8; ++j)
                pf[j] = ((const __bf16*)spg)[(kc*32 + quad*8 + j) * SPT + l16];
#pragma unroll
              for (int dn = 0; dn < 4; ++dn)
                oaccT[g][dn] = MFMA_BF16(vf[dn][kc], pf, oaccT[g][dn]);
            }
          }
        }
      }
    }

    float* scr = (float*)&sPT[w][0][0];
#pragma unroll
    for (int g = 0; g < 2; ++g)
#pragma unroll
      for (int r = 0; r < 4; ++r){
        float l = lsum[g][r];
        l += __shfl_xor(l, 1); l += __shfl_xor(l, 2);
        l += __shfl_xor(l, 4); l += __shfl_xor(l, 8);
        if (l16 == 0) scr[g*16 + quad*4 + r] = l;
      }
    float lrow[2];
#pragma unroll
    for (int g = 0; g < 2; ++g) lrow[g] = scr[g*16 + l16];

    size_t obase = ((size_t)(spl*32 + bh)) * 2048;
#pragma unroll
    for (int g = 0; g < 2; ++g){
      int row = rowbase + g*16 + l16;
      if (quad == 0) LP[obase + row] = lrow[g];
#pragma unroll
      for (int dn = 0; dn < 4; ++dn){
        ushort4 ov = { f2bf_rn(oaccT[g][dn][0]), f2bf_rn(oaccT[g][dn][1]),
                       f2bf_rn(oaccT[g][dn][2]), f2bf_rn(oaccT[g][dn][3]) };
        *(ushort4*)&OP[(obase + row) * 64 + dn*16 + quad*4] = ov;
      }
    }

    // protect sK / sPT reuse before the second item's staging begins
    __syncthreads();
  }
}

// ---------------- combine splits -> Ab (b, s, h*64+d) bf16 ----------------
__global__ void combine_kernel(const u16* __restrict__ OP, const float* __restrict__ LP,
                               u16* __restrict__ Ab){
  int idx = blockIdx.x * 256 + threadIdx.x;
  int dc = idx & 7, s = (idx >> 3) & 2047, bh = idx >> 14;
  size_t r0 = (size_t)bh * 2048 + s, r1 = (size_t)(32 + bh) * 2048 + s;
  float invl = 1.f / (LP[r0] + LP[r1]);
  union { uint4 v; u16 h[8]; } a0, a1, o;
  a0.v = *(const uint4*)&OP[r0 * 64 + dc*8];
  a1.v = *(const uint4*)&OP[r1 * 64 + dc*8];
#pragma unroll
  for (int j = 0; j < 8; ++j)
    o.h[j] = f2bf((bf2f(a0.h[j]) + bf2f(a1.h[j])) * invl);
  int b = bh >> 4, h = bh & 15;
  *(uint4*)&Ab[((size_t)(b*2048 + s)) * 1024 + h*64 + dc*8] = o.v;
}

// ---------------- launcher ----------------
extern "C" void kernel_launch(void* const* d_in, const int* in_sizes, int n_in,
                              void* d_out, int out_size, void* d_ws, size_t ws_size,
                              hipStream_t stream){
  (void)in_sizes; (void)n_in; (void)out_size; (void)ws_size;
  char* ws = (char*)d_ws;
  int*   flag  = (int*)ws;
  u16*   Xbf   = (u16*)(ws + XBF_OFF);
  u16*   Wd    = (u16*)(ws + WD_OFF);
  float* biasf = (float*)(ws + BIAS_OFF);
  u16*   Qb    = (u16*)(ws + QB_OFF);
  u16*   Kb    = (u16*)(ws + KB_OFF);
  u16*   Vt    = (u16*)(ws + VT_OFF);
  u16*   OP    = (u16*)(ws + OP_OFF);
  float* LP    = (float*)(ws + LP_OFF);
  u16*   Ab    = Xbf;   // x no longer needed after gemm_qkv; reuse as attn output

  QPtrs ptrs;
  for (int p = 0; p < 4; ++p){
    for (int wi = 0; wi < 4; ++wi) ptrs.w[p*4 + wi] = d_in[2 + p*5 + wi];
    ptrs.b[p] = d_in[2 + p*5 + 4];
  }

  prep_kernel<<<3072, 256, 0, stream>>>(d_in[0], ptrs, Xbf, Wd, biasf, flag);
  gemm_qkv_kernel<<<dim3(24, 32), 256, 0, stream>>>(Xbf, Wd, biasf, Qb, Kb, Vt);
  attn_kernel<<<dim3(32, 2, 16), 128, 0, stream>>>(Qb, Kb, Vt, OP, LP);
  combine_kernel<<<2048, 256, 0, stream>>>(OP, LP, Ab);
  gemm_o_kernel<<<dim3(8, 64), 256, 0, stream>>>(Ab, Wd + 3*1048576, biasf + 3072,
                                                 d_out, flag);
}

// Round 16
// 237.182 us; speedup vs baseline: 1.1791x; 1.0120x over previous
//
#include <hip/hip_runtime.h>
#include <stdint.h>

typedef unsigned short u16;
typedef unsigned int   u32;

#define NB   2
#define NS   2048
#define NDIM 1024
#define NH   16
#define NDH  64
// SCALE * log2(e) = 0.125 * 1.4426950408889634
#define QSCALE 0.18033688011112042f

typedef __bf16 bf16x8 __attribute__((ext_vector_type(8)));
typedef float  f32x4  __attribute__((ext_vector_type(4)));

#define MFMA_BF16(a,b,c) __builtin_amdgcn_mfma_f32_16x16x32_bf16((a),(b),(c),0,0,0)

// ---------------- ws layout (bytes) ----------------
#define XBF_OFF   (256)                          // 8 MB x bf16; reused as combined attention output Ab
#define WD_OFF    (XBF_OFF  + 8*1024*1024)       // 8 MB dense quaternion weights (q,k,v,o)
#define BIAS_OFF  (WD_OFF   + 8*1024*1024)       // 16 KB fp32 biases
#define QB_OFF    (BIAS_OFF + 16384)             // 8 MB Q (bh,s,d) bf16 (roped, pre-scaled)
#define KB_OFF    (QB_OFF   + 8*1024*1024)       // 8 MB K (bh,s,d) (roped)
#define VT_OFF    (KB_OFF   + 8*1024*1024)       // 8 MB V^T (bh,d,s)
#define OP_OFF    (VT_OFF   + 8*1024*1024)       // 16 MB O partials bf16 [split][bh][s][d]
#define LP_OFF    (OP_OFF   + 16*1024*1024)      // 512 KB l partials fp32 [split][bh][s]

__device__ __forceinline__ float bf2f(u16 h){
  union { u32 u; float f; } v; v.u = ((u32)h) << 16; return v.f;
}
__device__ __forceinline__ u16 f2bf(float f){
  union { float f; u32 u; } v; v.f = f;
  u32 r = (v.u >> 16) & 1u;
  return (u16)((v.u + 0x7fffu + r) >> 16);
}
// native RNE convert — compiler emits v_cvt_pk_bf16_f32 for pairs; same rounding
// as manual f2bf (bit-identical), ~5x fewer VALU ops.
__device__ __forceinline__ u16 f2bf_rn(float f){
  union { __bf16 h; u16 u; } v; v.h = (__bf16)f; return v.u;
}
__device__ __forceinline__ float load_val(const void* p, int i, int isbf){
  return isbf ? bf2f(((const u16*)p)[i]) : ((const float*)p)[i];
}
__device__ __forceinline__ void gl_lds16(const u16* g, u16* l){
  __builtin_amdgcn_global_load_lds(
      (__attribute__((address_space(1))) void*)(uintptr_t)g,
      (__attribute__((address_space(3))) void*)(uintptr_t)l,
      16, 0, 0);
}

// ---------------- fused prep: dtype detect + x->bf16 + weight build ----------------
// Weight build read-once: one thread computes all 4 c-rows from a single
// (vr,vi,vj,vk) read. Grid 3072: blocks [0,2048) convert x, [2048,3072) build.
struct QPtrs { const void* w[16]; const void* b[4]; };

__global__ void prep_kernel(const void* __restrict__ xin, QPtrs ptrs,
                            u16* __restrict__ xbf, u16* __restrict__ wd,
                            float* __restrict__ biasf, int* __restrict__ flag){
  __shared__ int cnt;
  if (threadIdx.x == 0) cnt = 0;
  __syncthreads();
  {
    const uint4* xv = (const uint4*)xin;
    uint4 v0 = xv[threadIdx.x * 2], v1 = xv[threadIdx.x * 2 + 1];
    const u16* hh = (const u16*)&v0;
    int ok = 0;
#pragma unroll
    for (int i = 0; i < 16; ++i){
      u16 h = (i < 8) ? hh[i] : ((const u16*)&v1)[i - 8];
      int e = (h >> 7) & 0xFF;
      if ((e > 96 && e < 158) || ((h & 0x7FFF) == 0)) ok++;
    }
    atomicAdd(&cnt, ok);
  }
  __syncthreads();
  int isbf = (cnt > 3600) ? 1 : 0;
  if (blockIdx.x == 0 && threadIdx.x == 0) *flag = isbf;

  int idx = blockIdx.x * 256 + threadIdx.x;

  if (blockIdx.x < 2048){
    // ---- conv part: blocks 0..2047 cover all 8 MB of x ----
    int t = idx;
    if (isbf){
      ((uint4*)xbf)[t] = ((const uint4*)xin)[t];
    } else {
      const float4* f4 = (const float4*)xin;
      float4 a = f4[2*t], b = f4[2*t+1];
      ushort4 lo = { f2bf(a.x), f2bf(a.y), f2bf(a.z), f2bf(a.w) };
      ushort4 hi = { f2bf(b.x), f2bf(b.y), f2bf(b.z), f2bf(b.w) };
      ((ushort4*)xbf)[2*t]   = lo;
      ((ushort4*)xbf)[2*t+1] = hi;
    }
  } else {
    // ---- weight build: blocks 2048..3071, one thread per (p,m,n) ----
    int wi = idx - 2048 * 256;            // [0, 262144)
    int n = wi & 255, m = (wi >> 8) & 255, p = wi >> 16;
    int src = m * 256 + n;
    float vr = load_val(ptrs.w[p*4+0], src, isbf);
    float vi = load_val(ptrs.w[p*4+1], src, isbf);
    float vj = load_val(ptrs.w[p*4+2], src, isbf);
    float vk = load_val(ptrs.w[p*4+3], src, isbf);
    ushort4 s0 = { f2bf(vr), f2bf(-vi), f2bf(-vj), f2bf(-vk) };
    ushort4 s1 = { f2bf(vi), f2bf(vr),  f2bf(-vj), f2bf(vk)  };
    ushort4 s2 = { f2bf(vj), f2bf(vi),  f2bf(vr),  f2bf(-vk) };
    ushort4 s3 = { f2bf(vk), f2bf(-vi), f2bf(vj),  f2bf(vr)  };
    u16* base = &wd[(size_t)p * 1048576 + (size_t)(4*m) * 1024 + 4*n];
    *(ushort4*)(base)        = s0;
    *(ushort4*)(base + 1024) = s1;
    *(ushort4*)(base + 2048) = s2;
    *(ushort4*)(base + 3072) = s3;
    if (wi < 4096){
      int pp = wi >> 10, oo = wi & 1023;
      biasf[wi] = load_val(ptrs.b[pp], oo, isbf);
    }
  }
}

// ---------------- GEMM: X*Wqkv^T, fused bias+RoPE epilogue ----------------
// Proven 128^2 triple-buffer counted-vmcnt form + T1 XCD-aware block swizzle
// (bijective: 768 blocks = 8 XCDs x 96).
__global__ __launch_bounds__(256)
void gemm_qkv_kernel(const u16* __restrict__ A, const u16* __restrict__ Bw,
                     const float* __restrict__ bias,
                     u16* __restrict__ qb, u16* __restrict__ kb, u16* __restrict__ vt){
  __shared__ u16 sA[3][128 * 32];
  __shared__ u16 sB[3][128 * 32];
  int tid = threadIdx.x, w = tid >> 6, lane = tid & 63, quad = lane >> 4, l16 = lane & 15;

  // XCD swizzle: hw block i runs work ((i&7)*96 + (i>>3))
  int lid = (int)blockIdx.y * 24 + (int)blockIdx.x;
  int swz = (lid & 7) * 96 + (lid >> 3);
  int n0 = (swz % 24) * 128, m0 = (swz / 24) * 128;

  f32x4 acc[4][4];
#pragma unroll
  for (int i = 0; i < 4; ++i)
#pragma unroll
    for (int j = 0; j < 4; ++j) acc[i][j] = (f32x4){0.f, 0.f, 0.f, 0.f};

  // staging: lane -> (row rl, chunk pos cp); fetch global chunk cp ^ ((rl>>1)&3)
  int cp = lane & 3, rl = lane >> 2;
  int gc = (cp ^ ((rl >> 1) & 3)) * 8;
  const u16* ga = A  + (size_t)(m0 + w*16 + rl) * 1024 + gc;
  const u16* gb = Bw + (size_t)(n0 + w*16 + rl) * 1024 + gc;
  int ldo = w * 512 + lane * 8;
  int xorv = ((l16 >> 1) & 3) * 8;
  int mw = (w & 1) * 64, nw = (w >> 1) * 64;

  auto stage = [&](int k0, int b){
#pragma unroll
    for (int i = 0; i < 2; ++i){
      gl_lds16(ga + (size_t)i * 65536 + k0, &sA[b][ldo + i * 2048]);
      gl_lds16(gb + (size_t)i * 65536 + k0, &sB[b][ldo + i * 2048]);
    }
  };

  stage(0, 0);
  stage(32, 1);
  asm volatile("s_waitcnt vmcnt(4)" ::: "memory");   // tile 0 landed, tile 1 in flight
  __builtin_amdgcn_s_barrier();

  int bcur = 0, bnxt = 2;   // compute buffer, stage-target buffer = (it+2)%3
  for (int it = 0; it < 32; ++it){
    if (it < 30) stage((it + 2) * 32, bnxt);
    const u16* cA = sA[bcur];
    const u16* cB = sB[bcur];
    bf16x8 af[4], bfr[4];
#pragma unroll
    for (int mt = 0; mt < 4; ++mt)
      af[mt] = *(const bf16x8*)&cA[(mw + mt*16 + l16) * 32 + (quad*8 ^ xorv)];
#pragma unroll
    for (int nt = 0; nt < 4; ++nt)
      bfr[nt] = *(const bf16x8*)&cB[(nw + nt*16 + l16) * 32 + (quad*8 ^ xorv)];
#pragma unroll
    for (int mt = 0; mt < 4; ++mt)
#pragma unroll
      for (int nt = 0; nt < 4; ++nt)
        acc[mt][nt] = MFMA_BF16(af[mt], bfr[nt], acc[mt][nt]);

    // drain stage(it+1) (needed next body); keep stage(it+2) flying
    if (it < 30) asm volatile("s_waitcnt vmcnt(4)" ::: "memory");
    else         asm volatile("s_waitcnt vmcnt(0)" ::: "memory");
    __builtin_amdgcn_s_barrier();
    bcur = (bcur == 2) ? 0 : bcur + 1;
    bnxt = (bnxt == 2) ? 0 : bnxt + 1;
  }

  int proj = n0 >> 10;    // uniform per block (proj boundary is a multiple of 128)
  if (proj == 2){
    // V^T: [bh][d][s]
#pragma unroll
    for (int mt = 0; mt < 4; ++mt){
      int row = m0 + mw + mt*16 + quad*4;
      int b = row >> 11, seq0 = row & 2047;
#pragma unroll
      for (int nt = 0; nt < 4; ++nt){
        int col = n0 + nw + nt*16 + l16;
        int o = col & 1023, h = o >> 6, d = o & 63;
        float bv = bias[col];
        ushort4 pv = { f2bf_rn(acc[mt][nt][0] + bv), f2bf_rn(acc[mt][nt][1] + bv),
                       f2bf_rn(acc[mt][nt][2] + bv), f2bf_rn(acc[mt][nt][3] + bv) };
        *(ushort4*)&vt[((size_t)((b*16 + h) * 64 + d)) * 2048 + seq0] = pv;
      }
    }
  } else {
    // Q/K with fused RoPE: out = co*v + sgn*si*partner  (partner = lane xor (ax+1))
    float sc = (proj == 0) ? QSCALE : 1.0f;
    u16* dst = proj ? kb : qb;
    int c = l16 & 3;
#pragma unroll
    for (int nt = 0; nt < 4; ++nt){
      int col = n0 + nw + nt*16 + l16;
      int o = col & 1023, h = o >> 6, d = o & 63;
      int g = d >> 2;
      int ax = g % 3;
      int mask = ax + 1;
      int tbl = (ax == 0) ? 0xA : (ax == 1 ? 0x6 : 0xC);   // '+' bits by component
      float sgn = ((tbl >> c) & 1) ? 1.f : -1.f;
      float inv = __builtin_amdgcn_exp2f(-(float)g * 0.8304820237218405f); // 10000^(-g/16)
      float bv = bias[col];
#pragma unroll
      for (int mt = 0; mt < 4; ++mt){
        int row0 = m0 + mw + mt*16 + quad*4;
        int b = row0 >> 11, s0 = row0 & 2047;
        size_t obase = ((size_t)((b*16 + h) * 2048 + s0)) * 64 + d;
#pragma unroll
        for (int r = 0; r < 4; ++r){
          float v = acc[mt][nt][r] + bv;
          float vp = __shfl_xor(v, mask);
          float ang = (float)(s0 + r) * inv;
          float co = __cosf(ang) * sc;
          float si = __sinf(ang) * sc * sgn;
          dst[obase + (size_t)r * 64] = f2bf_rn(co * v + si * vp);
        }
      }
    }
  }
}

// ---------------- GEMM: attn-out * Wo^T -> d_out ----------------
// Proven round-1/2 form: triple buffer, depth-2 prefetch, counted vmcnt(3).
// Round-16: + T1 XCD-aware block swizzle (bijective: 512 blocks = 8 XCDs x 64)
// — each XCD gets a contiguous run of m-panels so the 2 MB Wo stays resident in
// its L2 across the 8 m-panels it serves (B re-read 64x across the grid).
__global__ __launch_bounds__(256)
void gemm_o_kernel(const u16* __restrict__ A, const u16* __restrict__ Bw,
                   const float* __restrict__ bias, void* __restrict__ dout,
                   const int* __restrict__ flag){
  __shared__ u16 sA[3][64 * 32];
  __shared__ u16 sB[3][128 * 32];
  int tid = threadIdx.x, w = tid >> 6, lane = tid & 63, quad = lane >> 4, l16 = lane & 15;

  // XCD swizzle: hw block i runs work ((i&7)*64 + (i>>3))
  int lid = (int)blockIdx.y * 8 + (int)blockIdx.x;
  int swz = (lid & 7) * 64 + (lid >> 3);
  int n0 = (swz & 7) * 128, m0 = (swz >> 3) * 64;

  f32x4 acc[2][4];
#pragma unroll
  for (int i = 0; i < 2; ++i)
#pragma unroll
    for (int j = 0; j < 4; ++j) acc[i][j] = (f32x4){0.f, 0.f, 0.f, 0.f};

  int cp = lane & 3, rl = lane >> 2;
  int gc = (cp ^ ((rl >> 1) & 3)) * 8;
  int xorv = ((l16 >> 1) & 3) * 8;
  int mw = (w & 1) * 32, nw = (w >> 1) * 64;

  auto stage = [&](int k0, int b){
#pragma unroll
    for (int i = 0; i < 3; ++i){
      int ch = w * 3 + i;                 // 12 chunks: 4 sA + 8 sB
      int lr = (ch < 4 ? ch : ch - 4) * 16 + rl;
      int eo = (ch < 4 ? ch : ch - 4) * 512 + lane * 8;
      if (ch < 4) gl_lds16(A  + (size_t)(m0 + lr) * 1024 + k0 + gc, &sA[b][eo]);
      else        gl_lds16(Bw + (size_t)(n0 + lr) * 1024 + k0 + gc, &sB[b][eo]);
    }
  };

  stage(0, 0);
  stage(32, 1);
  asm volatile("s_waitcnt vmcnt(3)" ::: "memory");   // tile 0 landed, tile 1 in flight
  __builtin_amdgcn_s_barrier();

  int bcur = 0, bnxt = 2;
  for (int it = 0; it < 32; ++it){
    if (it < 30) stage((it + 2) * 32, bnxt);
    const u16* cA = sA[bcur];
    const u16* cB = sB[bcur];
    bf16x8 af[2], bfr[4];
#pragma unroll
    for (int mt = 0; mt < 2; ++mt)
      af[mt] = *(const bf16x8*)&cA[(mw + mt*16 + l16) * 32 + (quad*8 ^ xorv)];
#pragma unroll
    for (int nt = 0; nt < 4; ++nt)
      bfr[nt] = *(const bf16x8*)&cB[(nw + nt*16 + l16) * 32 + (quad*8 ^ xorv)];
#pragma unroll
    for (int mt = 0; mt < 2; ++mt)
#pragma unroll
      for (int nt = 0; nt < 4; ++nt)
        acc[mt][nt] = MFMA_BF16(af[mt], bfr[nt], acc[mt][nt]);

    if (it < 30) asm volatile("s_waitcnt vmcnt(3)" ::: "memory");
    else         asm volatile("s_waitcnt vmcnt(0)" ::: "memory");
    __builtin_amdgcn_s_barrier();
    bcur = (bcur == 2) ? 0 : bcur + 1;
    bnxt = (bnxt == 2) ? 0 : bnxt + 1;
  }

  int isbf = *flag;
#pragma unroll
  for (int mt = 0; mt < 2; ++mt){
    int row = m0 + mw + mt*16 + quad*4;
#pragma unroll
    for (int nt = 0; nt < 4; ++nt){
      int col = n0 + nw + nt*16 + l16;
      float bv = bias[col];
#pragma unroll
      for (int r = 0; r < 4; ++r){
        float val = acc[mt][nt][r] + bv;
        size_t addr = (size_t)(row + r) * 1024 + col;
        if (isbf) ((u16*)dout)[addr] = f2bf(val);
        else      ((float*)dout)[addr] = val;
      }
    }
  }
}

// ---------------- flash attention v8 (converged optimum: 47.8-49.1 us) ----------------
// 2-warp blocks (4/CU), 64-row slabs, pair-balanced splits, XCD-clustered
// bijective lid decode, per-g P-scratch. The work-per-block axis is falsified
// in BOTH directions: 128-row slabs (R12) lost to TLP collapse, 32-row slabs
// (R14) lost 2x to doubled per-tile fixed cost. This form is the optimum.
#define SPT 20

__global__ __launch_bounds__(128, 2)
void attn_kernel(const u16* __restrict__ Q, const u16* __restrict__ K,
                 const u16* __restrict__ Vt, u16* __restrict__ OP,
                 float* __restrict__ LP){
  __shared__ u16 sK[2][4096];           // 64 x 64 K-tile, double buffered (16 KB)
  __shared__ u16 sPT[2][2][64 * SPT];   // [warp][g] P-transpose scratch (10 KB)
  int lid = (int)blockIdx.x + 32 * (int)blockIdx.y + 64 * (int)blockIdx.z;
  int bh  = (lid & 7) * 4 + ((lid >> 3) & 3);
  int spl = (lid >> 5) & 1;
  int z   = lid >> 6;
  int tid = threadIdx.x, w = tid >> 6, lane = tid & 63, quad = lane >> 4, l16 = lane & 15;
  size_t kbase = (size_t)bh * 2048 * 64;
  size_t vbase = (size_t)bh * 64 * 2048;

  auto stage = [&](int kt, int b){
    int kcol = kt * 64;
#pragma unroll
    for (int p = 0; p < 4; ++p){
      int sb = (w*4 + p) * 64;          // wave-uniform LDS base (gl_lds requirement)
      int slot = sb + lane;
      int row = slot >> 3, dc = (slot & 7) ^ (row & 7);
      gl_lds16(K + kbase + (size_t)(kcol + row) * 64 + dc*8, &sK[b][sb * 8]);
    }
  };

  for (int item = 0; item < 2; ++item){
    int s2 = item ? z : 31 - z;         // q-slab index, rows [s2*64, s2*64+63]
    int rowbase = s2 * 64 + w * 32;

    bf16x8 qf[2][2];
#pragma unroll
    for (int g = 0; g < 2; ++g)
#pragma unroll
      for (int kc = 0; kc < 2; ++kc)
        qf[g][kc] = *(const bf16x8*)(Q + kbase + (size_t)(rowbase + g*16 + l16) * 64 + kc*32 + quad*8);

    f32x4 oaccT[2][4];
    float lsum[2][4];
#pragma unroll
    for (int g = 0; g < 2; ++g)
#pragma unroll
      for (int i = 0; i < 4; ++i){ oaccT[g][i] = (f32x4){0.f,0.f,0.f,0.f}; lsum[g][i] = 0.f; }

    int c = (s2 + 2) >> 1;              // ceil((s2+1)/2)
    int kt0 = spl ? c : 0;
    int ntiles = spl ? (s2 + 1 - c) : c;

    stage(kt0, 0);
    for (int i = 0; i < ntiles; ++i){
      int kcol = (kt0 + i) * 64;
      __syncthreads();
      if (i + 1 < ntiles) stage(kt0 + i + 1, (i + 1) & 1);
      const u16* bK = sK[i & 1];

      if (kcol <= rowbase + 31){
        bf16x8 vf[4][2];
#pragma unroll
        for (int dn = 0; dn < 4; ++dn)
#pragma unroll
          for (int kc = 0; kc < 2; ++kc)
            vf[dn][kc] = *(const bf16x8*)(Vt + vbase + (size_t)(dn*16 + l16) * 2048
                                          + kcol + kc*32 + quad*8);
        bf16x8 bk[2][4];
#pragma unroll
        for (int kc = 0; kc < 2; ++kc)
#pragma unroll
          for (int nt = 0; nt < 4; ++nt){
            int rw = nt*16 + l16;
            int ch = ((kc*4 + quad) ^ (rw & 7)) * 8;
            bk[kc][nt] = *(const bf16x8*)&bK[rw*64 + ch];
          }
#pragma unroll
        for (int g = 0; g < 2; ++g){
          int G0 = rowbase + g*16;
          if (kcol <= G0 + 15){
            u16* spg = &sPT[w][g][0];
            f32x4 sacc[4];
#pragma unroll
            for (int nt = 0; nt < 4; ++nt) sacc[nt] = (f32x4){0.f,0.f,0.f,0.f};
#pragma unroll
            for (int kc = 0; kc < 2; ++kc)
#pragma unroll
              for (int nt = 0; nt < 4; ++nt)
                sacc[nt] = MFMA_BF16(qf[g][kc], bk[kc][nt], sacc[nt]);

            if (kcol + 63 > G0){
#pragma unroll
              for (int nt = 0; nt < 4; ++nt){
                int col = kcol + nt*16 + l16;
                ushort4 pv;
#pragma unroll
                for (int r = 0; r < 4; ++r){
                  int row = G0 + quad*4 + r;
                  float pp = (col <= row) ? __builtin_amdgcn_exp2f(sacc[nt][r]) : 0.f;
                  lsum[g][r] += pp;
                  ((u16*)&pv)[r] = f2bf_rn(pp);
                }
                *(ushort4*)&spg[(nt*16 + l16) * SPT + quad*4] = pv;
              }
            } else {
#pragma unroll
              for (int nt = 0; nt < 4; ++nt){
                ushort4 pv;
#pragma unroll
                for (int r = 0; r < 4; ++r){
                  float pp = __builtin_amdgcn_exp2f(sacc[nt][r]);
                  lsum[g][r] += pp;
                  ((u16*)&pv)[r] = f2bf_rn(pp);
                }
                *(ushort4*)&spg[(nt*16 + l16) * SPT + quad*4] = pv;
              }
            }
#pragma unroll
            for (int kc = 0; kc < 2; ++kc){
              bf16x8 pf;
#pragma unroll
              for (int j = 0; j < 8; ++j)
                pf[j] = ((const __bf16*)spg)[(kc*32 + quad*8 + j) * SPT + l16];
#pragma unroll
              for (int dn = 0; dn < 4; ++dn)
                oaccT[g][dn] = MFMA_BF16(vf[dn][kc], pf, oaccT[g][dn]);
            }
          }
        }
      }
    }

    float* scr = (float*)&sPT[w][0][0];
#pragma unroll
    for (int g = 0; g < 2; ++g)
#pragma unroll
      for (int r = 0; r < 4; ++r){
        float l = lsum[g][r];
        l += __shfl_xor(l, 1); l += __shfl_xor(l, 2);
        l += __shfl_xor(l, 4); l += __shfl_xor(l, 8);
        if (l16 == 0) scr[g*16 + quad*4 + r] = l;
      }
    float lrow[2];
#pragma unroll
    for (int g = 0; g < 2; ++g) lrow[g] = scr[g*16 + l16];

    size_t obase = ((size_t)(spl*32 + bh)) * 2048;
#pragma unroll
    for (int g = 0; g < 2; ++g){
      int row = rowbase + g*16 + l16;
      if (quad == 0) LP[obase + row] = lrow[g];
#pragma unroll
      for (int dn = 0; dn < 4; ++dn){
        ushort4 ov = { f2bf_rn(oaccT[g][dn][0]), f2bf_rn(oaccT[g][dn][1]),
                       f2bf_rn(oaccT[g][dn][2]), f2bf_rn(oaccT[g][dn][3]) };
        *(ushort4*)&OP[(obase + row) * 64 + dn*16 + quad*4] = ov;
      }
    }

    // protect sK / sPT reuse before the second item's staging begins
    __syncthreads();
  }
}

// ---------------- combine splits -> Ab (b, s, h*64+d) bf16 ----------------
__global__ void combine_kernel(const u16* __restrict__ OP, const float* __restrict__ LP,
                               u16* __restrict__ Ab){
  int idx = blockIdx.x * 256 + threadIdx.x;
  int dc = idx & 7, s = (idx >> 3) & 2047, bh = idx >> 14;
  size_t r0 = (size_t)bh * 2048 + s, r1 = (size_t)(32 + bh) * 2048 + s;
  float invl = 1.f / (LP[r0] + LP[r1]);
  union { uint4 v; u16 h[8]; } a0, a1, o;
  a0.v = *(const uint4*)&OP[r0 * 64 + dc*8];
  a1.v = *(const uint4*)&OP[r1 * 64 + dc*8];
#pragma unroll
  for (int j = 0; j < 8; ++j)
    o.h[j] = f2bf((bf2f(a0.h[j]) + bf2f(a1.h[j])) * invl);
  int b = bh >> 4, h = bh & 15;
  *(uint4*)&Ab[((size_t)(b*2048 + s)) * 1024 + h*64 + dc*8] = o.v;
}

// ---------------- launcher ----------------
extern "C" void kernel_launch(void* const* d_in, const int* in_sizes, int n_in,
                              void* d_out, int out_size, void* d_ws, size_t ws_size,
                              hipStream_t stream){
  (void)in_sizes; (void)n_in; (void)out_size; (void)ws_size;
  char* ws = (char*)d_ws;
  int*   flag  = (int*)ws;
  u16*   Xbf   = (u16*)(ws + XBF_OFF);
  u16*   Wd    = (u16*)(ws + WD_OFF);
  float* biasf = (float*)(ws + BIAS_OFF);
  u16*   Qb    = (u16*)(ws + QB_OFF);
  u16*   Kb    = (u16*)(ws + KB_OFF);
  u16*   Vt    = (u16*)(ws + VT_OFF);
  u16*   OP    = (u16*)(ws + OP_OFF);
  float* LP    = (float*)(ws + LP_OFF);
  u16*   Ab    = Xbf;   // x no longer needed after gemm_qkv; reuse as attn output

  QPtrs ptrs;
  for (int p = 0; p < 4; ++p){
    for (int wi = 0; wi < 4; ++wi) ptrs.w[p*4 + wi] = d_in[2 + p*5 + wi];
    ptrs.b[p] = d_in[2 + p*5 + 4];
  }

  prep_kernel<<<3072, 256, 0, stream>>>(d_in[0], ptrs, Xbf, Wd, biasf, flag);
  gemm_qkv_kernel<<<dim3(24, 32), 256, 0, stream>>>(Xbf, Wd, biasf, Qb, Kb, Vt);
  attn_kernel<<<dim3(32, 2, 16), 128, 0, stream>>>(Qb, Kb, Vt, OP, LP);
  combine_kernel<<<2048, 256, 0, stream>>>(OP, LP, Ab);
  gemm_o_kernel<<<dim3(8, 64), 256, 0, stream>>>(Ab, Wd + 3*1048576, biasf + 3072,
                                                 d_out, flag);
}